// Round 13
// baseline (11575.475 us; speedup 1.0000x reference)
//
#include <hip/hip_runtime.h>
#include <math.h>

#define SS   2048
#define HH   1024
#define HHF  512
#define NWG  96           // 64 rec WGs + 32 tau WGs
#define REC_WGS 64
#define NTH  512          // 8 waves; 2 rows/wave -> 16 rows/WG
#define NCNT 16           // striped arrive counters

__device__ __forceinline__ float dot4f(float4 a, float4 b){
  return a.x*b.x + a.y*b.y + a.z*b.z + a.w*b.w;
}

// relaxed agent-scope atomics -> sc1 (L2-bypass, coherent at L3)
__device__ __forceinline__ float2 aload2(const float* p){
  unsigned long long v = __hip_atomic_load((const unsigned long long*)p,
                                           __ATOMIC_RELAXED, __HIP_MEMORY_SCOPE_AGENT);
  union { unsigned long long u; float2 f; } c; c.u = v; return c.f;
}
__device__ __forceinline__ void astore1(float* p, float v){
  __hip_atomic_store(p, v, __ATOMIC_RELAXED, __HIP_MEMORY_SCOPE_AGENT);
}
__device__ __forceinline__ float aload1(const float* p){
  return __hip_atomic_load(p, __ATOMIC_RELAXED, __HIP_MEMORY_SCOPE_AGENT);
}
__device__ __forceinline__ unsigned uload(const unsigned* p){
  return __hip_atomic_load(p, __ATOMIC_RELAXED, __HIP_MEMORY_SCOPE_AGENT);
}

// ---------- transpose h-part of tau_w1: w1hT[m][i] = tau_w1[1024+i][m] ----------
__global__ __launch_bounds__(256) void transpose_w1h(const float* __restrict__ tw1,
                                                     float* __restrict__ w1hT){
  __shared__ float ts[32][33];
  int c  = threadIdx.x & 31;
  int r4 = (threadIdx.x >> 5) * 4;
  int bi = blockIdx.x * 32;
  int bm = blockIdx.y * 32;
  #pragma unroll
  for (int rr = 0; rr < 4; ++rr)
    ts[r4+rr][c] = tw1[(size_t)(1024 + bi + r4 + rr) * 512 + bm + c];
  __syncthreads();
  #pragma unroll
  for (int rr = 0; rr < 4; ++rr)
    w1hT[(size_t)(bm + r4 + rr) * 1024 + bi + c] = ts[c][r4+rr];
}

// ---------- xtau[r][m] = X[r][:] @ tau_w1[:1024][m] + b1[m] ----------
__global__ __launch_bounds__(256) void gemm_xtau(const float* __restrict__ X,
                                                 const float* __restrict__ tw1,
                                                 const float* __restrict__ b1,
                                                 float* __restrict__ xtau){
  __shared__ float Xs[16][68];
  __shared__ float Ws[16][68];
  const int tid = threadIdx.x;
  const int tx = tid & 15, ty = tid >> 4;
  const int rowbase = blockIdx.y * 64;
  const int colbase = blockIdx.x * 64;
  const int xr  = tid >> 2,  xk4 = (tid & 3) * 4;
  const int wr  = tid >> 4,  wc4 = (tid & 15) * 4;
  float acc[4][4];
  #pragma unroll
  for (int i=0;i<4;++i){
    #pragma unroll
    for (int j=0;j<4;++j) acc[i][j]=0.f;
  }
  for (int k0 = 0; k0 < 1024; k0 += 16){
    float4 xv = *(const float4*)&X  [(size_t)(rowbase + xr)*1024 + k0 + xk4];
    float4 wv = *(const float4*)&tw1[(size_t)(k0 + wr)*512 + colbase + wc4];
    __syncthreads();
    Xs[xk4+0][xr]=xv.x; Xs[xk4+1][xr]=xv.y; Xs[xk4+2][xr]=xv.z; Xs[xk4+3][xr]=xv.w;
    *(float4*)&Ws[wr][wc4] = wv;
    __syncthreads();
    #pragma unroll
    for (int kk=0;kk<16;++kk){
      float4 av = *(const float4*)&Xs[kk][ty*4];
      float4 bv = *(const float4*)&Ws[kk][tx*4];
      acc[0][0]+=av.x*bv.x; acc[0][1]+=av.x*bv.y; acc[0][2]+=av.x*bv.z; acc[0][3]+=av.x*bv.w;
      acc[1][0]+=av.y*bv.x; acc[1][1]+=av.y*bv.y; acc[1][2]+=av.y*bv.z; acc[1][3]+=av.y*bv.w;
      acc[2][0]+=av.z*bv.x; acc[2][1]+=av.z*bv.y; acc[2][2]+=av.z*bv.z; acc[2][3]+=av.z*bv.w;
      acc[3][0]+=av.w*bv.x; acc[3][1]+=av.w*bv.y; acc[3][2]+=av.w*bv.z; acc[3][3]+=av.w*bv.w;
    }
  }
  float4 bias = *(const float4*)&b1[colbase + tx*4];
  #pragma unroll
  for (int i=0;i<4;++i){
    float4 o;
    o.x=acc[i][0]+bias.x; o.y=acc[i][1]+bias.y; o.z=acc[i][2]+bias.z; o.w=acc[i][3]+bias.w;
    *(float4*)&xtau[(size_t)(rowbase + ty*4 + i)*512 + colbase + tx*4] = o;
  }
}

// ---------- persistent liquid recurrence ----------
// R2/R11 proven skeleton, scaled to 96 WGs x 512 thr (half the sync
// participants, half the broadcast fan-in), with two latency hides:
//  - speculative tagged consumer loads issued before the poll (drain-before-
//    arrive guarantees the single post-release revalidate pass succeeds)
//  - next-step x/xtau prefetch issued during the poll window
// All sync ops are the measured-safe sc1 relaxed atomics. No unverified
// coherence semantics anywhere.
__global__ __launch_bounds__(512, 1) void liquid_kernel(
    const float* __restrict__ X, const float* __restrict__ Wrec,
    const float* __restrict__ w1hT, const float* __restrict__ tw2,
    const float* __restrict__ tb2, const float* __restrict__ lng,
    const float* __restrict__ lnb, const float* __restrict__ xtau,
    unsigned* __restrict__ cnt, float* __restrict__ fbuf,
    float* __restrict__ taup, float* __restrict__ out)
{
  __shared__ float hs[2][4][1024];

  const int tid  = threadIdx.x;
  const int wv   = tid >> 6;      // wave id; waves 0..3 own batch wv in consume
  const int lane = tid & 63;
  const int wg   = blockIdx.x;

  for (int p = tid; p < 8192; p += NTH) (&hs[0][0][0])[p] = 0.f;

  // 16 virtual rows per WG (2 per wave) resident in VGPRs
  float4 wreg[2][4];
  #pragma unroll
  for (int rr = 0; rr < 2; ++rr){
    const float* wrow = (wg < REC_WGS)
        ? (Wrec + (size_t)(wg*16 + wv*2 + rr)*1024)
        : (w1hT + (size_t)((wg - REC_WGS)*16 + wv*2 + rr)*1024);
    #pragma unroll
    for (int k = 0; k < 4; ++k)
      wreg[rr][k] = *(const float4*)&wrow[4*lane + 256*k];
  }
  float4 g4[4], be4[4];
  #pragma unroll
  for (int k = 0; k < 4; ++k){
    g4[k]  = *(const float4*)&lng[4*lane + 256*k];
    be4[k] = *(const float4*)&lnb[4*lane + 256*k];
  }
  const float b2 = tb2[0];
  float w2r0 = 0.f, w2r1 = 0.f;
  if (wg >= REC_WGS){
    w2r0 = tw2[(wg - REC_WGS)*16 + wv*2 + 0];
    w2r1 = tw2[(wg - REC_WGS)*16 + wv*2 + 1];
  }
  const int xrow = (lane < 8) ? (wg*16 + wv*2 + (lane >> 2)) : 0;
  const int xb   = lane & 3;

  // prefetch xpre for t=0
  float xpre = 0.f;
  if (lane < 8){
    if (wg < REC_WGS) xpre = X[((size_t)xb*SS + 0)*HH + xrow];
    else              xpre = xtau[((size_t)xb*SS + 0)*HHF + (wg-REC_WGS)*16 + wv*2 + (lane>>2)];
  }
  __syncthreads();

  for (int t = 0; t < SS; ++t){
    const int cur = t & 1, nxt = cur ^ 1;
    // mod-4 tags: slot holds step t or t-2 only (barrier-bounded skew);
    // bases differ by 4 (f) / 16 (tau) -> outside windows; init 0 / poison invalid.
    const float fbase = 2.f*(float)((t & 3) + 1);   // 2,4,6,8   window +-1.05
    const float tbase = 8.f*(float)((t & 3) + 1);   // 8,16,24,32 window +-2.0

    // ---- matvec: 2 rows x 4 batches per wave, weights in regs, h from LDS
    float acc[8];
    #pragma unroll
    for (int a=0;a<8;++a) acc[a]=0.f;
    #pragma unroll
    for (int k=0;k<4;++k){
      const int off = 4*lane + 256*k;
      float4 h0 = *(const float4*)&hs[cur][0][off];
      float4 h1 = *(const float4*)&hs[cur][1][off];
      float4 h2 = *(const float4*)&hs[cur][2][off];
      float4 h3 = *(const float4*)&hs[cur][3][off];
      #pragma unroll
      for (int rr=0;rr<2;++rr){
        acc[rr*4+0] += dot4f(wreg[rr][k], h0);
        acc[rr*4+1] += dot4f(wreg[rr][k], h1);
        acc[rr*4+2] += dot4f(wreg[rr][k], h2);
        acc[rr*4+3] += dot4f(wreg[rr][k], h3);
      }
    }
    #pragma unroll
    for (int a=0;a<8;++a){
      float v = acc[a];
      #pragma unroll
      for (int o=32;o>0;o>>=1) v += __shfl_xor(v, o, 64);
      acc[a]=v;
    }
    float sel = acc[0];
    sel = (lane==1)?acc[1]:sel; sel = (lane==2)?acc[2]:sel;
    sel = (lane==3)?acc[3]:sel; sel = (lane==4)?acc[4]:sel;
    sel = (lane==5)?acc[5]:sel; sel = (lane==6)?acc[6]:sel;
    sel = (lane==7)?acc[7]:sel;
    float fval = tanhf(xpre + sel);

    // ---- tagged publish (plain sc1 stores to distinct slots; zero RMW)
    if (wg < REC_WGS){
      if (lane < 8)
        astore1(&fbuf[cur*4096 + (lane&3)*1024 + wg*16 + wv*2 + (lane>>2)],
                fbase + fval);
    } else {
      float w2s = (lane & 4) ? w2r1 : w2r0;
      float contrib = fval * w2s;
      contrib += __shfl_xor(contrib, 4, 64);   // sum this wave's 2 rows
      if (lane < 4)
        astore1(&taup[cur*1024 + lane*256 + (wg - REC_WGS)*8 + wv],
                tbase + contrib);
    }

    // ---- DRAIN: publishes ACKed at L3 (vmcnt(0) inside __syncthreads)
    __syncthreads();
    // ---- arrive: 16 striped counters (6-deep chains)
    if (tid == 0)
      __hip_atomic_fetch_add(&cnt[(wg & (NCNT-1))*16], 1u,
                             __ATOMIC_RELAXED, __HIP_MEMORY_SCOPE_AGENT);

    // ---- speculative consumer loads (waves 0..3): fly during the poll
    const float* fb = fbuf + cur*4096 + wv*1024;
    float2 pr[8]; float tv[4];
    if (wv < 4){
      #pragma unroll
      for (int q=0;q<8;++q)
        pr[q] = aload2(&fb[(q>>1)*256 + 4*lane + (q&1)*2]);
      #pragma unroll
      for (int j=0;j<4;++j)
        tv[j] = aload1(&taup[cur*1024 + wv*256 + lane + 64*j]);
    }
    // ---- prefetch next step's x/xtau (pure function of t+1, hidden here)
    if (lane < 8 && t + 1 < SS){
      if (wg < REC_WGS) xpre = X[((size_t)xb*SS + (t+1))*HH + xrow];
      else              xpre = xtau[((size_t)xb*SS + (t+1))*HHF + (wg-REC_WGS)*16 + wv*2 + (lane>>2)];
    }

    // ---- poll: wave0 lanes 0..15 ONLY (uniform exit), butterfly-16, backoff
    if (wv == 0 && lane < NCNT){
      const unsigned tgt = (unsigned)NWG * (unsigned)(t + 1);
      int guard = 0;
      while (true){
        unsigned s = uload(&cnt[lane*16]);
        #pragma unroll
        for (int o=8;o>0;o>>=1) s += (unsigned)__shfl_xor((int)s, o, 64);
        if (s >= tgt) break;                 // same s on all 16 active lanes
        __builtin_amdgcn_s_sleep(1);
        if (++guard > 100000) break;         // fail-visible, never watchdog
      }
    }
    __syncthreads();   // release

    if (wv < 4){
      // ---- revalidate tags; reload invalid once (guaranteed valid now)
      int guard = 0;
      while (true){
        bool all = true;
        #pragma unroll
        for (int q=0;q<8;++q){
          bool ok = (fabsf(pr[q].x - fbase) < 1.05f) && (fabsf(pr[q].y - fbase) < 1.05f);
          if (!ok){ all = false; pr[q] = aload2(&fb[(q>>1)*256 + 4*lane + (q&1)*2]); }
        }
        #pragma unroll
        for (int j=0;j<4;++j){
          if (!(fabsf(tv[j] - tbase) < 2.0f)){
            all = false; tv[j] = aload1(&taup[cur*1024 + wv*256 + lane + 64*j]);
          }
        }
        if (all) break;
        if (++guard > 2000) break;           // bounded; wrong data fails absmax
      }

      // ---- tau (intra-wave reduce of 256 partials: 4 per lane)
      float tpart = (tv[0]-tbase)+(tv[1]-tbase)+(tv[2]-tbase)+(tv[3]-tbase);
      #pragma unroll
      for (int o=32;o>0;o>>=1) tpart += __shfl_xor(tpart, o, 64);
      float pre = tpart + b2;
      float sig = 1.f / (1.f + expf(-pre));
      float al  = 0.1f / (1.f + 4.f*sig);

      // ---- h' + LN (fully intra-wave, batch = wv)
      float s1 = 0.f, s2 = 0.f;
      float4 hp4[4];
      #pragma unroll
      for (int k=0;k<4;++k){
        const int off = 4*lane + 256*k;
        float4 h4 = *(const float4*)&hs[cur][wv][off];
        float4 hp;
        hp.x = h4.x + al*((pr[2*k  ].x - fbase) - h4.x);
        hp.y = h4.y + al*((pr[2*k  ].y - fbase) - h4.y);
        hp.z = h4.z + al*((pr[2*k+1].x - fbase) - h4.z);
        hp.w = h4.w + al*((pr[2*k+1].y - fbase) - h4.w);
        hp4[k] = hp;
        s1 += hp.x + hp.y + hp.z + hp.w;
        s2 += hp.x*hp.x + hp.y*hp.y + hp.z*hp.z + hp.w*hp.w;
      }
      #pragma unroll
      for (int o=32;o>0;o>>=1){
        s1 += __shfl_xor(s1, o, 64);
        s2 += __shfl_xor(s2, o, 64);
      }
      float mu   = s1 * (1.f/1024.f);
      float var  = s2 * (1.f/1024.f) - mu*mu;
      float rstd = rsqrtf(var + 1e-5f);
      #pragma unroll
      for (int k=0;k<4;++k){
        const int off = 4*lane + 256*k;
        float4 hp = hp4[k];
        float4 o4;
        o4.x = (hp.x - mu)*rstd*g4[k].x + be4[k].x;
        o4.y = (hp.y - mu)*rstd*g4[k].y + be4[k].y;
        o4.z = (hp.z - mu)*rstd*g4[k].z + be4[k].z;
        o4.w = (hp.w - mu)*rstd*g4[k].w + be4[k].w;
        *(float4*)&hs[nxt][wv][off] = o4;
        if (wg < 16 && (wg >> 2) == k && (lane >> 4) == (wg & 3))
          *(float4*)&out[((size_t)wv*SS + t)*HH + off] = o4;
      }
    }

    // ---- end-of-step: wait only LDS writes (global stores keep flying)
    asm volatile("s_waitcnt lgkmcnt(0)" ::: "memory");
    __builtin_amdgcn_sched_barrier(0);
    __builtin_amdgcn_s_barrier();
  }
}

// ---------- out = sc + 0.01*(liq - sc), in place over liq ----------
__global__ __launch_bounds__(256) void finalize_kernel(const float* __restrict__ X,
                                                       const float* __restrict__ cw,
                                                       float* __restrict__ out){
  size_t gid = (size_t)blockIdx.x * 256 + threadIdx.x;
  size_t gi  = gid * 4;
  int b   = (int)(gi >> 21);
  int rem = (int)(gi & 2097151);
  int t   = rem >> 10;
  int i   = rem & 1023;
  float4 l4 = *(const float4*)&out[gi];
  const float* xb = X + ((size_t)b*SS)*HH + i;
  float4 z4 = make_float4(0.f,0.f,0.f,0.f);
  float4 xk0 = (t >= 3) ? *(const float4*)&xb[(size_t)(t-3)*HH] : z4;
  float4 xk1 = (t >= 2) ? *(const float4*)&xb[(size_t)(t-2)*HH] : z4;
  float4 xk2 = (t >= 1) ? *(const float4*)&xb[(size_t)(t-1)*HH] : z4;
  float4 xk3 =            *(const float4*)&xb[(size_t)t*HH];
  float4 cw0 = *(const float4*)&cw[(i+0)*4];
  float4 cw1 = *(const float4*)&cw[(i+1)*4];
  float4 cw2 = *(const float4*)&cw[(i+2)*4];
  float4 cw3 = *(const float4*)&cw[(i+3)*4];
  float4 sc;
  sc.x = cw0.x*xk0.x + cw0.y*xk1.x + cw0.z*xk2.x + cw0.w*xk3.x;
  sc.y = cw1.x*xk0.y + cw1.y*xk1.y + cw1.z*xk2.y + cw1.w*xk3.y;
  sc.z = cw2.x*xk0.z + cw2.y*xk1.z + cw2.z*xk2.z + cw2.w*xk3.z;
  sc.w = cw3.x*xk0.w + cw3.y*xk1.w + cw3.z*xk2.w + cw3.w*xk3.w;
  float4 o;
  o.x = sc.x + 0.01f*(l4.x - sc.x);
  o.y = sc.y + 0.01f*(l4.y - sc.y);
  o.z = sc.z + 0.01f*(l4.z - sc.z);
  o.w = sc.w + 0.01f*(l4.w - sc.w);
  *(float4*)&out[gi] = o;
}

extern "C" void kernel_launch(void* const* d_in, const int* in_sizes, int n_in,
                              void* d_out, int out_size, void* d_ws, size_t ws_size,
                              hipStream_t stream) {
  const float* X     = (const float*)d_in[0];
  const float* convw = (const float*)d_in[1];
  const float* Wrec  = (const float*)d_in[2];
  const float* tw1   = (const float*)d_in[3];
  const float* tb1   = (const float*)d_in[4];
  const float* tw2   = (const float*)d_in[5];
  const float* tb2   = (const float*)d_in[6];
  const float* lng   = (const float*)d_in[7];
  const float* lnb   = (const float*)d_in[8];
  float* out = (float*)d_out;
  float* wsf = (float*)d_ws;

  unsigned* cnt = (unsigned*)d_ws;      // 16 counters @ 64B spacing = 256 dwords
  float* fbuf = wsf + 256;              // 2 x 4 x 1024 tagged f
  float* taup = wsf + 8448;             // 2 x 4 x 256 tagged tau partials
  float* w1hT = wsf + 10496;            // 512 x 1024
  float* xtau = w1hT + 512*1024;        // 8192 x 512

  hipMemsetAsync(d_ws, 0, 41984, stream);  // counters + all tags invalid
  transpose_w1h<<<dim3(32,16), dim3(256), 0, stream>>>(tw1, w1hT);
  gemm_xtau   <<<dim3(8,128),  dim3(256), 0, stream>>>(X, tw1, tb1, xtau);
  liquid_kernel<<<dim3(NWG),   dim3(NTH), 0, stream>>>(X, Wrec, w1hT, tw2, tb2,
                                                       lng, lnb, xtau, cnt, fbuf,
                                                       taup, out);
  finalize_kernel<<<dim3(8192), dim3(256), 0, stream>>>(X, convw, out);
}

// Round 14
// 10026.133 us; speedup vs baseline: 1.1545x; 1.1545x over previous
//
#include <hip/hip_runtime.h>
#include <math.h>

#define SS   2048
#define HH   1024
#define HHF  512
#define NWG  192          // 4 domains x 48 WGs
#define DWG  48           // WGs per domain (one domain = one batch)
#define RECWG 32          // local WGs 0..31: rec rows; 32..47: tau rows
#define NTH  256

__device__ __forceinline__ float dot4f(float4 a, float4 b){
  return a.x*b.x + a.y*b.y + a.z*b.z + a.w*b.w;
}

// relaxed agent-scope atomics -> sc1 (L2-bypass, coherent at L3) — proven safe
__device__ __forceinline__ float2 aload2(const float* p){
  unsigned long long v = __hip_atomic_load((const unsigned long long*)p,
                                           __ATOMIC_RELAXED, __HIP_MEMORY_SCOPE_AGENT);
  union { unsigned long long u; float2 f; } c; c.u = v; return c.f;
}
__device__ __forceinline__ void astore1(float* p, float v){
  __hip_atomic_store(p, v, __ATOMIC_RELAXED, __HIP_MEMORY_SCOPE_AGENT);
}
__device__ __forceinline__ float aload1(const float* p){
  return __hip_atomic_load(p, __ATOMIC_RELAXED, __HIP_MEMORY_SCOPE_AGENT);
}
__device__ __forceinline__ unsigned uload(const unsigned* p){
  return __hip_atomic_load(p, __ATOMIC_RELAXED, __HIP_MEMORY_SCOPE_AGENT);
}

// ---------- transpose h-part of tau_w1: w1hT[m][i] = tau_w1[1024+i][m] ----------
__global__ __launch_bounds__(256) void transpose_w1h(const float* __restrict__ tw1,
                                                     float* __restrict__ w1hT){
  __shared__ float ts[32][33];
  int c  = threadIdx.x & 31;
  int r4 = (threadIdx.x >> 5) * 4;
  int bi = blockIdx.x * 32;
  int bm = blockIdx.y * 32;
  #pragma unroll
  for (int rr = 0; rr < 4; ++rr)
    ts[r4+rr][c] = tw1[(size_t)(1024 + bi + r4 + rr) * 512 + bm + c];
  __syncthreads();
  #pragma unroll
  for (int rr = 0; rr < 4; ++rr)
    w1hT[(size_t)(bm + r4 + rr) * 1024 + bi + c] = ts[c][r4+rr];
}

// ---------- xtau[r][m] = X[r][:] @ tau_w1[:1024][m] + b1[m] ----------
__global__ __launch_bounds__(256) void gemm_xtau(const float* __restrict__ X,
                                                 const float* __restrict__ tw1,
                                                 const float* __restrict__ b1,
                                                 float* __restrict__ xtau){
  __shared__ float Xs[16][68];
  __shared__ float Ws[16][68];
  const int tid = threadIdx.x;
  const int tx = tid & 15, ty = tid >> 4;
  const int rowbase = blockIdx.y * 64;
  const int colbase = blockIdx.x * 64;
  const int xr  = tid >> 2,  xk4 = (tid & 3) * 4;
  const int wr  = tid >> 4,  wc4 = (tid & 15) * 4;
  float acc[4][4];
  #pragma unroll
  for (int i=0;i<4;++i){
    #pragma unroll
    for (int j=0;j<4;++j) acc[i][j]=0.f;
  }
  for (int k0 = 0; k0 < 1024; k0 += 16){
    float4 xv = *(const float4*)&X  [(size_t)(rowbase + xr)*1024 + k0 + xk4];
    float4 wv = *(const float4*)&tw1[(size_t)(k0 + wr)*512 + colbase + wc4];
    __syncthreads();
    Xs[xk4+0][xr]=xv.x; Xs[xk4+1][xr]=xv.y; Xs[xk4+2][xr]=xv.z; Xs[xk4+3][xr]=xv.w;
    *(float4*)&Ws[wr][wc4] = wv;
    __syncthreads();
    #pragma unroll
    for (int kk=0;kk<16;++kk){
      float4 av = *(const float4*)&Xs[kk][ty*4];
      float4 bv = *(const float4*)&Ws[kk][tx*4];
      acc[0][0]+=av.x*bv.x; acc[0][1]+=av.x*bv.y; acc[0][2]+=av.x*bv.z; acc[0][3]+=av.x*bv.w;
      acc[1][0]+=av.y*bv.x; acc[1][1]+=av.y*bv.y; acc[1][2]+=av.y*bv.z; acc[1][3]+=av.y*bv.w;
      acc[2][0]+=av.z*bv.x; acc[2][1]+=av.z*bv.y; acc[2][2]+=av.z*bv.z; acc[2][3]+=av.z*bv.w;
      acc[3][0]+=av.w*bv.x; acc[3][1]+=av.w*bv.y; acc[3][2]+=av.w*bv.z; acc[3][3]+=av.w*bv.w;
    }
  }
  float4 bias = *(const float4*)&b1[colbase + tx*4];
  #pragma unroll
  for (int i=0;i<4;++i){
    float4 o;
    o.x=acc[i][0]+bias.x; o.y=acc[i][1]+bias.y; o.z=acc[i][2]+bias.z; o.w=acc[i][3]+bias.w;
    *(float4*)&xtau[(size_t)(rowbase + ty*4 + i)*512 + colbase + tx*4] = o;
  }
}

// ---------- persistent liquid recurrence: 4 INDEPENDENT batch domains ----------
// Batches are fully independent recurrences. Domain d = batch d: 48 WGs,
// own counters/f-buffer/tau-slots. Per domain, R2's exact proven protocol:
// publish (sc1 stores, distinct slots) -> DRAIN (vmcnt0 in syncthreads) ->
// arrive (4 striped counters) -> tid0 no-backoff poll -> release -> load ONCE.
// vs R2: 4x less broadcast volume (4KB/WG not 16KB), tail over 48 WGs not 192.
// Weights duplicated per domain: 8 rows/wave x 16 floats = 128 VGPRs.
__global__ __launch_bounds__(256, 1) void liquid_kernel(
    const float* __restrict__ X, const float* __restrict__ Wrec,
    const float* __restrict__ w1hT, const float* __restrict__ tw2,
    const float* __restrict__ tb2, const float* __restrict__ lng,
    const float* __restrict__ lnb, const float* __restrict__ xtau,
    unsigned* __restrict__ cnt, float* __restrict__ fbuf,
    float* __restrict__ taup, float* __restrict__ out)
{
  __shared__ float hs[2][1024];
  __shared__ float stats_lds[8];

  const int tid  = threadIdx.x;
  const int wv   = tid >> 6;
  const int lane = tid & 63;
  const int d     = blockIdx.x & 3;   // domain == batch (round-robins XCDs)
  const int local = blockIdx.x >> 2;  // 0..47 within domain

  for (int p = tid; p < 2048; p += NTH) (&hs[0][0])[p] = 0.f;

  // 32 rows per WG (8 per wave), weights resident in VGPRs (128 regs)
  const bool isrec = (local < RECWG);
  const int base = isrec ? (local*32 + wv*8) : ((local - RECWG)*32 + wv*8);
  float4 wreg[8][4];
  #pragma unroll
  for (int rr = 0; rr < 8; ++rr){
    const float* wrow = isrec ? (Wrec + (size_t)(base + rr)*1024)
                              : (w1hT + (size_t)(base + rr)*1024);
    #pragma unroll
    for (int k = 0; k < 4; ++k)
      wreg[rr][k] = *(const float4*)&wrow[4*lane + 256*k];
  }
  float4 g4 = *(const float4*)&lng[4*tid];
  float4 be4 = *(const float4*)&lnb[4*tid];
  const float b2 = tb2[0];
  float w2r = 0.f;
  if (!isrec && lane < 8) w2r = tw2[base + lane];
  __syncthreads();

  for (int t = 0; t < SS; ++t){
    const int cur = t & 1, nxt = cur ^ 1;

    // ---- x / xtau preload for this wave's 8 rows (lanes 0..7)
    float xpre = 0.f;
    if (lane < 8){
      xpre = isrec ? X   [((size_t)d*SS + t)*HH  + base + lane]
                   : xtau[((size_t)d*SS + t)*HHF + base + lane];
    }

    // ---- matvec: 8 rows x 1 batch per wave, weights in regs, h from LDS
    float acc[8];
    #pragma unroll
    for (int a=0;a<8;++a) acc[a]=0.f;
    #pragma unroll
    for (int k=0;k<4;++k){
      float4 h4 = *(const float4*)&hs[cur][4*lane + 256*k];
      #pragma unroll
      for (int rr=0;rr<8;++rr) acc[rr] += dot4f(wreg[rr][k], h4);
    }
    #pragma unroll
    for (int a=0;a<8;++a){
      float v = acc[a];
      #pragma unroll
      for (int o=32;o>0;o>>=1) v += __shfl_xor(v, o, 64);
      acc[a]=v;
    }
    float sel = acc[0];
    sel = (lane==1)?acc[1]:sel; sel = (lane==2)?acc[2]:sel;
    sel = (lane==3)?acc[3]:sel; sel = (lane==4)?acc[4]:sel;
    sel = (lane==5)?acc[5]:sel; sel = (lane==6)?acc[6]:sel;
    sel = (lane==7)?acc[7]:sel;
    float fval = tanhf(xpre + sel);

    // ---- publish (sc1 stores, distinct slots, zero RMW)
    if (isrec){
      if (lane < 8)
        astore1(&fbuf[cur*4096 + d*1024 + base + lane], fval);
    } else {
      float contrib = (lane < 8) ? fval * w2r : 0.f;
      contrib += __shfl_xor(contrib, 1, 8);
      contrib += __shfl_xor(contrib, 2, 8);
      contrib += __shfl_xor(contrib, 4, 8);
      if (lane == 0)
        astore1(&taup[cur*256 + d*64 + (local - RECWG)*4 + wv], contrib);
    }

    // ---- DRAIN (vmcnt0 inside __syncthreads), then arrive
    __syncthreads();
    if (tid == 0)
      __hip_atomic_fetch_add(&cnt[(d*4 + (local & 3))*16], 1u,
                             __ATOMIC_RELAXED, __HIP_MEMORY_SCOPE_AGENT);

    // ---- poll: tid 0 only, sum domain's 4 counters, no backoff (R2 style)
    if (tid == 0){
      const unsigned tgt = (unsigned)DWG * (unsigned)(t + 1);
      int guard = 0;
      while (guard < 50000){
        unsigned s = uload(&cnt[(d*4 + 0)*16])
                   + uload(&cnt[(d*4 + 1)*16])
                   + uload(&cnt[(d*4 + 2)*16])
                   + uload(&cnt[(d*4 + 3)*16]);
        if (s >= tgt) break;
        ++guard;
      }
    }
    __syncthreads();   // release

    // ---- load ONCE: 4 f values (this thread's elems) + 64 tau partials
    const float* fb = fbuf + cur*4096 + d*1024 + 4*tid;
    float2 lo = aload2(fb);
    float2 hi = aload2(fb + 2);
    float tpart = aload1(&taup[cur*256 + d*64 + lane]);
    #pragma unroll
    for (int o=32;o>0;o>>=1) tpart += __shfl_xor(tpart, o, 64);
    const float sig = 1.f / (1.f + expf(-(tpart + b2)));
    const float al  = 0.1f / (1.f + 4.f*sig);

    // ---- h' (this thread's 4 elems) + LN stats
    float4 h4 = *(const float4*)&hs[cur][4*tid];
    float4 hp;
    hp.x = h4.x + al*(lo.x - h4.x);
    hp.y = h4.y + al*(lo.y - h4.y);
    hp.z = h4.z + al*(hi.x - h4.z);
    hp.w = h4.w + al*(hi.y - h4.w);
    float s1 = hp.x + hp.y + hp.z + hp.w;
    float s2 = hp.x*hp.x + hp.y*hp.y + hp.z*hp.z + hp.w*hp.w;
    #pragma unroll
    for (int o=32;o>0;o>>=1){
      s1 += __shfl_xor(s1, o, 64);
      s2 += __shfl_xor(s2, o, 64);
    }
    if (lane == 0){ stats_lds[wv*2] = s1; stats_lds[wv*2+1] = s2; }
    __syncthreads();
    const float s1t = stats_lds[0] + stats_lds[2] + stats_lds[4] + stats_lds[6];
    const float s2t = stats_lds[1] + stats_lds[3] + stats_lds[5] + stats_lds[7];
    const float mu   = s1t * (1.f/1024.f);
    const float var  = s2t * (1.f/1024.f) - mu*mu;
    const float rstd = rsqrtf(var + 1e-5f);
    float4 o4;
    o4.x = (hp.x - mu)*rstd*g4.x + be4.x;
    o4.y = (hp.y - mu)*rstd*g4.y + be4.y;
    o4.z = (hp.z - mu)*rstd*g4.z + be4.z;
    o4.w = (hp.w - mu)*rstd*g4.w + be4.w;
    *(float4*)&hs[nxt][4*tid] = o4;
    if (local == 0)
      *(float4*)&out[((size_t)d*SS + t)*HH + 4*tid] = o4;

    // ---- end-of-step: wait only LDS writes (global stores keep flying)
    asm volatile("s_waitcnt lgkmcnt(0)" ::: "memory");
    __builtin_amdgcn_sched_barrier(0);
    __builtin_amdgcn_s_barrier();
  }
}

// ---------- out = sc + 0.01*(liq - sc), in place over liq ----------
__global__ __launch_bounds__(256) void finalize_kernel(const float* __restrict__ X,
                                                       const float* __restrict__ cw,
                                                       float* __restrict__ out){
  size_t gid = (size_t)blockIdx.x * 256 + threadIdx.x;
  size_t gi  = gid * 4;
  int b   = (int)(gi >> 21);
  int rem = (int)(gi & 2097151);
  int t   = rem >> 10;
  int i   = rem & 1023;
  float4 l4 = *(const float4*)&out[gi];
  const float* xb = X + ((size_t)b*SS)*HH + i;
  float4 z4 = make_float4(0.f,0.f,0.f,0.f);
  float4 xk0 = (t >= 3) ? *(const float4*)&xb[(size_t)(t-3)*HH] : z4;
  float4 xk1 = (t >= 2) ? *(const float4*)&xb[(size_t)(t-2)*HH] : z4;
  float4 xk2 = (t >= 1) ? *(const float4*)&xb[(size_t)(t-1)*HH] : z4;
  float4 xk3 =            *(const float4*)&xb[(size_t)t*HH];
  float4 cw0 = *(const float4*)&cw[(i+0)*4];
  float4 cw1 = *(const float4*)&cw[(i+1)*4];
  float4 cw2 = *(const float4*)&cw[(i+2)*4];
  float4 cw3 = *(const float4*)&cw[(i+3)*4];
  float4 sc;
  sc.x = cw0.x*xk0.x + cw0.y*xk1.x + cw0.z*xk2.x + cw0.w*xk3.x;
  sc.y = cw1.x*xk0.y + cw1.y*xk1.y + cw1.z*xk2.y + cw1.w*xk3.y;
  sc.z = cw2.x*xk0.z + cw2.y*xk1.z + cw2.z*xk2.z + cw2.w*xk3.z;
  sc.w = cw3.x*xk0.w + cw3.y*xk1.w + cw3.z*xk2.w + cw3.w*xk3.w;
  float4 o;
  o.x = sc.x + 0.01f*(l4.x - sc.x);
  o.y = sc.y + 0.01f*(l4.y - sc.y);
  o.z = sc.z + 0.01f*(l4.z - sc.z);
  o.w = sc.w + 0.01f*(l4.w - sc.w);
  *(float4*)&out[gi] = o;
}

extern "C" void kernel_launch(void* const* d_in, const int* in_sizes, int n_in,
                              void* d_out, int out_size, void* d_ws, size_t ws_size,
                              hipStream_t stream) {
  const float* X     = (const float*)d_in[0];
  const float* convw = (const float*)d_in[1];
  const float* Wrec  = (const float*)d_in[2];
  const float* tw1   = (const float*)d_in[3];
  const float* tb1   = (const float*)d_in[4];
  const float* tw2   = (const float*)d_in[5];
  const float* tb2   = (const float*)d_in[6];
  const float* lng   = (const float*)d_in[7];
  const float* lnb   = (const float*)d_in[8];
  float* out = (float*)d_out;
  float* wsf = (float*)d_ws;

  unsigned* cnt = (unsigned*)d_ws;      // 16 counters (4/domain) @ 64B spacing
  float* fbuf = wsf + 256;              // 2 x 4 x 1024 f values
  float* taup = wsf + 8448;             // 2 x 4 x 64 tau partials
  float* w1hT = wsf + 8960;             // 512 x 1024
  float* xtau = w1hT + 512*1024;        // 8192 x 512

  hipMemsetAsync(d_ws, 0, 1024, stream);   // arrive counters only
  transpose_w1h<<<dim3(32,16), dim3(256), 0, stream>>>(tw1, w1hT);
  gemm_xtau   <<<dim3(8,128),  dim3(256), 0, stream>>>(X, tw1, tb1, xtau);
  liquid_kernel<<<dim3(NWG),   dim3(NTH), 0, stream>>>(X, Wrec, w1hT, tw2, tb2,
                                                       lng, lnb, xtau, cnt, fbuf,
                                                       taup, out);
  finalize_kernel<<<dim3(8192), dim3(256), 0, stream>>>(X, convw, out);
}